// Round 9
// baseline (314.462 us; speedup 1.0000x reference)
//
#include <hip/hip_runtime.h>
#include <hip/hip_fp16.h>

#define NN 50000
#define EE 800000
#define ET 850000          // EE + NN self-loops
#define NEG 0.2f
#define SCAN_B 1024
#define NBLK ((NN + SCAN_B - 1) / SCAN_B)   // 49

__device__ __forceinline__ float leaky(float x) { return fmaxf(x, NEG * x); }
__device__ __forceinline__ float elu_f(float x) { return x > 0.f ? x : expm1f(x); }

struct alignas(8) half4 { __half2 a, b; };

typedef _Float16 half8_t __attribute__((ext_vector_type(8)));
typedef float float4_t __attribute__((ext_vector_type(4)));

// ---------------- CSR build (by destination) ----------------
__global__ void hist_k(const int* __restrict__ ei, int* __restrict__ counts,
                       int* __restrict__ rank) {
    int i = blockIdx.x * blockDim.x + threadIdx.x;
    if (i >= ET) return;
    int dst = (i < EE) ? __builtin_nontemporal_load(ei + EE + i) : (i - EE);
    int r = atomicAdd(&counts[dst], 1);
    __builtin_nontemporal_store(r, rank + i);
}

__global__ void scan1_k(const int* __restrict__ counts, int* __restrict__ rp,
                        int* __restrict__ bsums) {
    __shared__ int lsum[256];
    int base = blockIdx.x * SCAN_B;
    int v[4];
    int tsum = 0;
#pragma unroll
    for (int j = 0; j < 4; ++j) {
        int i = base + threadIdx.x * 4 + j;
        v[j] = (i < NN) ? counts[i] : 0;
        tsum += v[j];
    }
    lsum[threadIdx.x] = tsum;
    __syncthreads();
    for (int off = 1; off < 256; off <<= 1) {
        int t = (threadIdx.x >= off) ? lsum[threadIdx.x - off] : 0;
        __syncthreads();
        lsum[threadIdx.x] += t;
        __syncthreads();
    }
    int excl = lsum[threadIdx.x] - tsum;
#pragma unroll
    for (int j = 0; j < 4; ++j) {
        int i = base + threadIdx.x * 4 + j;
        if (i < NN) rp[i] = excl;
        excl += v[j];
    }
    if (threadIdx.x == 255) bsums[blockIdx.x] = lsum[255];
}

__global__ void scan2_k(int* __restrict__ bsums, int* __restrict__ rp) {
    int lane = threadIdx.x;
    int v = (lane < NBLK) ? bsums[lane] : 0;
    int orig = v;
    for (int off = 1; off < 64; off <<= 1) {
        int t = __shfl_up(v, off, 64);
        if (lane >= off) v += t;
    }
    if (lane < NBLK) bsums[lane] = v - orig;
    if (lane == 63) rp[NN] = v;
}

__global__ void scan3_k(int* __restrict__ rp, const int* __restrict__ bsums) {
    int add = bsums[blockIdx.x];
    int base = blockIdx.x * SCAN_B + threadIdx.x * 4;
#pragma unroll
    for (int j = 0; j < 4; ++j) {
        int i = base + j;
        if (i < NN) rp[i] += add;
    }
}

__global__ void scatter_k(const int* __restrict__ ei, const int* __restrict__ rp,
                          const int* __restrict__ rank, int* __restrict__ csr) {
    int i = blockIdx.x * blockDim.x + threadIdx.x;
    if (i >= ET) return;
    int src, dst;
    if (i < EE) {
        src = __builtin_nontemporal_load(ei + i);
        dst = __builtin_nontemporal_load(ei + EE + i);
    } else {
        src = dst = i - EE;
    }
    int r = __builtin_nontemporal_load(rank + i);
    csr[rp[dst] + r] = src;   // normal store: let dirty lines merge in L2
}

// ---- transpose W1,W2 (fp32 [128][128] k-major) -> fp16 [128][128] n-major ----
__global__ void wt_k(const float* __restrict__ W1, const float* __restrict__ W2,
                     __half* __restrict__ Wt1, __half* __restrict__ Wt2) {
    int i = blockIdx.x * 256 + threadIdx.x;   // 32768 threads
    const float* W = (i < 16384) ? W1 : W2;
    __half* Wt = (i < 16384) ? Wt1 : Wt2;
    int j = i & 16383;
    int k = j >> 7, n = j & 127;
    Wt[n * 128 + k] = __float2half(W[j]);
}

// ---- MFMA GEMM [nrows,128]@[128,128] -> fp16, fused attention logits ----
__global__ __launch_bounds__(256)
void gemm_mfma_k(const float* __restrict__ Xf, const __half* __restrict__ Xh,
                 const __half* __restrict__ Wt, __half* __restrict__ Yh, int nrows,
                 const float* __restrict__ att_s, const float* __restrict__ att_d,
                 float* __restrict__ asb, float* __restrict__ adb) {
    __shared__ __align__(16) __half cst[4][16 * 128];   // 16 KB
    int lane = threadIdx.x & 63;
    int wid  = threadIdx.x >> 6;
    int n = lane & 15, quad = lane >> 4;
    int row0 = (blockIdx.x * 4 + wid) * 16;

    float atts_r[8], attd_r[8];
#pragma unroll
    for (int t = 0; t < 8; ++t) {
        atts_r[t] = att_s[t * 16 + n];
        attd_r[t] = att_d[t * 16 + n];
    }

    float4_t acc[8];
#pragma unroll
    for (int t = 0; t < 8; ++t) acc[t] = (float4_t){0.f, 0.f, 0.f, 0.f};
    int rA = row0 + n; if (rA >= nrows) rA = nrows - 1;
#pragma unroll
    for (int ch = 0; ch < 4; ++ch) {
        half8_t a;
        if (Xh) {
            a = __builtin_nontemporal_load(
                    (const half8_t*)(Xh + (size_t)rA * 128 + ch * 32 + quad * 8));
        } else {
            const float4_t* xp = (const float4_t*)(Xf + (size_t)rA * 128 + ch * 32 + quad * 8);
            float4_t f0 = __builtin_nontemporal_load(xp);
            float4_t f1 = __builtin_nontemporal_load(xp + 1);
            a = (half8_t){(_Float16)f0.x, (_Float16)f0.y, (_Float16)f0.z, (_Float16)f0.w,
                          (_Float16)f1.x, (_Float16)f1.y, (_Float16)f1.z, (_Float16)f1.w};
        }
#pragma unroll
        for (int t = 0; t < 8; ++t) {
            half8_t b = *(const half8_t*)(Wt + (t * 16 + n) * 128 + ch * 32 + quad * 8);
            acc[t] = __builtin_amdgcn_mfma_f32_16x16x32_f16(a, b, acc[t], 0, 0, 0);
        }
    }

    // fused alpha: reduce acc * att over the 16 col-lanes of each quad
#pragma unroll
    for (int rg = 0; rg < 4; ++rg) {
        float ps[4], pd[4];
#pragma unroll
        for (int h = 0; h < 4; ++h) {
            ps[h] = acc[2*h][rg] * atts_r[2*h] + acc[2*h+1][rg] * atts_r[2*h+1];
            pd[h] = acc[2*h][rg] * attd_r[2*h] + acc[2*h+1][rg] * attd_r[2*h+1];
#pragma unroll
            for (int mask = 1; mask < 16; mask <<= 1) {
                ps[h] += __shfl_xor(ps[h], mask, 64);
                pd[h] += __shfl_xor(pd[h], mask, 64);
            }
        }
        int row = row0 + quad * 4 + rg;
        if (n == 0 && row < nrows) {
#pragma unroll
            for (int h = 0; h < 4; ++h) {
                asb[row * 4 + h] = ps[h];
                adb[row * 4 + h] = pd[h];
            }
        }
    }

    // C store: stage fp16 tile in LDS, then coalesced row writes
#pragma unroll
    for (int rg = 0; rg < 4; ++rg)
#pragma unroll
        for (int t = 0; t < 8; ++t)
            cst[wid][(quad * 4 + rg) * 128 + t * 16 + n] = __float2half(acc[t][rg]);
    __syncthreads();
    {
        int chunk = lane & 15;
        int rsub  = lane >> 4;
#pragma unroll
        for (int it = 0; it < 4; ++it) {
            int row = it * 4 + rsub;
            int grow = row0 + row;
            if (grow < nrows) {
                half8_t v = *(const half8_t*)(&cst[wid][row * 128 + chunk * 8]);
                *(half8_t*)(Yh + (size_t)grow * 128 + chunk * 8) = v;
            }
        }
    }
}

// ---- fused softmax + aggregation + bias + ELU (+ optional layer-3 projection) ----
// half-wave (32 lanes) per node, 4 channels per lane, 8 edges deep,
// csr indices for chunk k+1 prefetched while chunk k's gathers are in flight
__global__ __launch_bounds__(256)
void agg_k(const __half* __restrict__ Hh, const float* __restrict__ asb,
           const float* __restrict__ adb, const int* __restrict__ rp,
           const int* __restrict__ csr, const float* __restrict__ bias,
           __half* __restrict__ Y,
           const float* __restrict__ W3, const float* __restrict__ s3w,
           const float* __restrict__ d3w, float* __restrict__ h3,
           float* __restrict__ as3, float* __restrict__ ad3) {
    int lane = threadIdx.x & 63;
    int hw = lane >> 5;
    int l  = lane & 31;                   // owns channels l*4 .. l*4+3
    int n = blockIdx.x * 8 + (threadIdx.x >> 6) * 2 + hw;
    if (n >= NN) return;
    int hd = l >> 3;
    float ad = adb[n * 4 + hd];
    float acc0 = 0.f, acc1 = 0.f, acc2 = 0.f, acc3 = 0.f, den = 0.f;
    int e = rp[n], end = rp[n + 1], last = end - 1;

    int s[8];
#pragma unroll
    for (int j = 0; j < 8; ++j) {
        int i = e + j;
        s[j] = csr[i <= last ? i : last];
    }
    for (int base = e; base < end; base += 8) {
        // prefetch next chunk's indices (clamped -> always safe, branch-free)
        int sn[8];
#pragma unroll
        for (int j = 0; j < 8; ++j) {
            int i = base + 8 + j;
            sn[j] = csr[i <= last ? i : last];
        }
        float a[8];
#pragma unroll
        for (int j = 0; j < 8; ++j) a[j] = asb[s[j] * 4 + hd] + ad;
        float2 hraw[8];
#pragma unroll
        for (int j = 0; j < 8; ++j)
            hraw[j] = ((const float2*)(Hh + (size_t)s[j] * 128))[l];
#pragma unroll
        for (int j = 0; j < 8; ++j) {
            float w = __expf(leaky(a[j]));
            w = (base + j <= last) ? w : 0.f;   // mask duplicated tail edges
            den += w;
            const __half2* hp = (const __half2*)&hraw[j];
            float2 f01 = __half22float2(hp[0]);
            float2 f23 = __half22float2(hp[1]);
            acc0 += w * f01.x; acc1 += w * f01.y;
            acc2 += w * f23.x; acc3 += w * f23.y;
        }
#pragma unroll
        for (int j = 0; j < 8; ++j) s[j] = sn[j];
    }
    float4 bv = ((const float4*)bias)[l];
    float inv = 1.f / den;
    float o0 = elu_f(acc0 * inv + bv.x);
    float o1 = elu_f(acc1 * inv + bv.y);
    float o2 = elu_f(acc2 * inv + bv.z);
    float o3 = elu_f(acc3 * inv + bv.w);
    if (!W3) {
        half4 hv;
        hv.a = __floats2half2_rn(o0, o1);
        hv.b = __floats2half2_rn(o2, o3);
        ((half4*)(Y + (size_t)n * 128))[l] = hv;
    } else {
        float4 wa = ((const float4*)W3)[l * 2];
        float4 wb = ((const float4*)W3)[l * 2 + 1];
        float p0 = o0 * wa.x + o1 * wa.z + o2 * wb.x + o3 * wb.z;
        float p1 = o0 * wa.y + o1 * wa.w + o2 * wb.y + o3 * wb.w;
        for (int off = 16; off > 0; off >>= 1) {
            p0 += __shfl_down(p0, off, 32);
            p1 += __shfl_down(p1, off, 32);
        }
        if (l == 0) {
            h3[n * 2 + 0] = p0;
            h3[n * 2 + 1] = p1;
            as3[n] = p0 * s3w[0] + p1 * s3w[1];
            ad3[n] = p0 * d3w[0] + p1 * d3w[1];
        }
    }
}

// ---- layer-3 aggregation + log_softmax ----
__global__ void l3agg_k(const float* __restrict__ h3, const float* __restrict__ as3,
                        const float* __restrict__ ad3, const int* __restrict__ rp,
                        const int* __restrict__ csr, const float* __restrict__ b3,
                        float* __restrict__ out) {
    int n = blockIdx.x * blockDim.x + threadIdx.x;
    if (n >= NN) return;
    const float2* h2 = (const float2*)h3;
    float adn = ad3[n];
    float den = 0.f, a0 = 0.f, a1 = 0.f;
    int e = rp[n], end = rp[n + 1], last = end - 1;
    for (int base = e; base < end; base += 4) {
        int s[4]; float al[4]; float2 g[4];
#pragma unroll
        for (int j = 0; j < 4; ++j) {
            int i = base + j;
            s[j] = csr[i <= last ? i : last];
        }
#pragma unroll
        for (int j = 0; j < 4; ++j) al[j] = as3[s[j]] + adn;
#pragma unroll
        for (int j = 0; j < 4; ++j) g[j] = h2[s[j]];
#pragma unroll
        for (int j = 0; j < 4; ++j) {
            float w = __expf(leaky(al[j]));
            w = (base + j <= last) ? w : 0.f;
            den += w;
            a0 += w * g[j].x;
            a1 += w * g[j].y;
        }
    }
    float o0 = a0 / den + b3[0];
    float o1 = a1 / den + b3[1];
    float m = fmaxf(o0, o1);
    float lse = m + logf(__expf(o0 - m) + __expf(o1 - m));
    out[n * 2 + 0] = o0 - lse;
    out[n * 2 + 1] = o1 - lse;
}

extern "C" void kernel_launch(void* const* d_in, const int* in_sizes, int n_in,
                              void* d_out, int out_size, void* d_ws, size_t ws_size,
                              hipStream_t stream) {
    const float* x   = (const float*)d_in[0];
    const int*   ei  = (const int*)d_in[1];
    const float* W1  = (const float*)d_in[2];
    const float* as1 = (const float*)d_in[3];
    const float* ad1 = (const float*)d_in[4];
    const float* b1  = (const float*)d_in[5];
    const float* W2  = (const float*)d_in[6];
    const float* as2 = (const float*)d_in[7];
    const float* ad2 = (const float*)d_in[8];
    const float* b2  = (const float*)d_in[9];
    const float* W3  = (const float*)d_in[10];
    const float* s3w = (const float*)d_in[11];
    const float* d3w = (const float*)d_in[12];
    const float* b3  = (const float*)d_in[13];
    float* out = (float*)d_out;

    char* ws = (char*)d_ws;
    size_t off = 0;
    auto alloc = [&](size_t bytes) -> char* {
        char* p = ws + off;
        off = (off + bytes + 255) & ~(size_t)255;
        return p;
    };
    __half* hA    = (__half*)alloc((size_t)NN * 128 * 2);   // fp16 gather table
    __half* hBh   = (__half*)alloc((size_t)NN * 128 * 2);   // agg1 out (gemm2 in, fp16)
    float* asb    = (float*)alloc((size_t)NN * 4 * 4);
    float* adb    = (float*)alloc((size_t)NN * 4 * 4);
    int*   rp     = (int*)alloc((size_t)(NN + 1) * 4);
    int*   counts = (int*)alloc((size_t)NN * 4);
    int*   csr    = (int*)alloc((size_t)ET * 4);
    int*   rank   = (int*)alloc((size_t)ET * 4);
    int*   bsums  = (int*)alloc((size_t)NBLK * 4);
    __half* Wt1   = (__half*)alloc(128 * 128 * 2);
    __half* Wt2   = (__half*)alloc(128 * 128 * 2);
    float* h3     = (float*)alloc((size_t)NN * 2 * 4);
    float* s3     = (float*)alloc((size_t)NN * 4);
    float* d3     = (float*)alloc((size_t)NN * 4);

    // weight transposes (fp16), independent of everything else
    wt_k<<<128, 256, 0, stream>>>(W1, W2, Wt1, Wt2);

    // CSR by destination (shared by all 3 layers)
    (void)hipMemsetAsync(counts, 0, (size_t)NN * 4, stream);
    hist_k<<<(ET + 255) / 256, 256, 0, stream>>>(ei, counts, rank);
    scan1_k<<<NBLK, 256, 0, stream>>>(counts, rp, bsums);
    scan2_k<<<1, 64, 0, stream>>>(bsums, rp);
    scan3_k<<<NBLK, 256, 0, stream>>>(rp, bsums);
    scatter_k<<<(ET + 255) / 256, 256, 0, stream>>>(ei, rp, rank, csr);

    // Layer 1 (alpha fused into gemm epilogue)
    gemm_mfma_k<<<(NN + 63) / 64, 256, 0, stream>>>(x, nullptr, Wt1, hA, NN,
                                                    as1, ad1, asb, adb);
    agg_k<<<(NN + 7) / 8, 256, 0, stream>>>(hA, asb, adb, rp, csr, b1, hBh,
                                            nullptr, nullptr, nullptr,
                                            nullptr, nullptr, nullptr);

    // Layer 2 (+ fused layer-3 projection/logits in agg epilogue)
    gemm_mfma_k<<<(NN + 63) / 64, 256, 0, stream>>>(nullptr, hBh, Wt2, hA, NN,
                                                    as2, ad2, asb, adb);
    agg_k<<<(NN + 7) / 8, 256, 0, stream>>>(hA, asb, adb, rp, csr, b2, nullptr,
                                            W3, s3w, d3w, h3, s3, d3);

    // Layer 3 aggregation + log_softmax
    l3agg_k<<<(NN + 255) / 256, 256, 0, stream>>>(h3, s3, d3, rp, csr, b3, out);
}

// Round 10
// 293.894 us; speedup vs baseline: 1.0700x; 1.0700x over previous
//
#include <hip/hip_runtime.h>
#include <hip/hip_fp16.h>

#define NN 50000
#define EE 800000
#define ET 850000          // EE + NN self-loops
#define NEG 0.2f
#define SCAN_B 1024
#define NBLK ((NN + SCAN_B - 1) / SCAN_B)   // 49

__device__ __forceinline__ float leaky(float x) { return fmaxf(x, NEG * x); }
__device__ __forceinline__ float elu_f(float x) { return x > 0.f ? x : expm1f(x); }

struct alignas(8) half4 { __half2 a, b; };

typedef _Float16 half8_t __attribute__((ext_vector_type(8)));
typedef float float4_t __attribute__((ext_vector_type(4)));

// ---------------- CSR build (by destination) ----------------
__global__ void hist_k(const int* __restrict__ ei, int* __restrict__ counts,
                       int* __restrict__ rank) {
    int i = blockIdx.x * blockDim.x + threadIdx.x;
    if (i >= ET) return;
    int dst = (i < EE) ? __builtin_nontemporal_load(ei + EE + i) : (i - EE);
    int r = atomicAdd(&counts[dst], 1);
    __builtin_nontemporal_store(r, rank + i);
}

__global__ void scan1_k(const int* __restrict__ counts, int* __restrict__ rp,
                        int* __restrict__ bsums) {
    __shared__ int lsum[256];
    int base = blockIdx.x * SCAN_B;
    int v[4];
    int tsum = 0;
#pragma unroll
    for (int j = 0; j < 4; ++j) {
        int i = base + threadIdx.x * 4 + j;
        v[j] = (i < NN) ? counts[i] : 0;
        tsum += v[j];
    }
    lsum[threadIdx.x] = tsum;
    __syncthreads();
    for (int off = 1; off < 256; off <<= 1) {
        int t = (threadIdx.x >= off) ? lsum[threadIdx.x - off] : 0;
        __syncthreads();
        lsum[threadIdx.x] += t;
        __syncthreads();
    }
    int excl = lsum[threadIdx.x] - tsum;
#pragma unroll
    for (int j = 0; j < 4; ++j) {
        int i = base + threadIdx.x * 4 + j;
        if (i < NN) rp[i] = excl;
        excl += v[j];
    }
    if (threadIdx.x == 255) bsums[blockIdx.x] = lsum[255];
}

__global__ void scan2_k(int* __restrict__ bsums, int* __restrict__ rp) {
    int lane = threadIdx.x;
    int v = (lane < NBLK) ? bsums[lane] : 0;
    int orig = v;
    for (int off = 1; off < 64; off <<= 1) {
        int t = __shfl_up(v, off, 64);
        if (lane >= off) v += t;
    }
    if (lane < NBLK) bsums[lane] = v - orig;
    if (lane == 63) rp[NN] = v;
}

__global__ void scan3_k(int* __restrict__ rp, const int* __restrict__ bsums) {
    int add = bsums[blockIdx.x];
    int base = blockIdx.x * SCAN_B + threadIdx.x * 4;
#pragma unroll
    for (int j = 0; j < 4; ++j) {
        int i = base + j;
        if (i < NN) rp[i] += add;
    }
}

__global__ void scatter_k(const int* __restrict__ ei, const int* __restrict__ rp,
                          const int* __restrict__ rank, int* __restrict__ csr) {
    int i = blockIdx.x * blockDim.x + threadIdx.x;
    if (i >= ET) return;
    int src, dst;
    if (i < EE) {
        src = __builtin_nontemporal_load(ei + i);
        dst = __builtin_nontemporal_load(ei + EE + i);
    } else {
        src = dst = i - EE;
    }
    int r = __builtin_nontemporal_load(rank + i);
    csr[rp[dst] + r] = src;   // normal store: let dirty lines merge in L2
}

// ---- transpose W1,W2 (fp32 [128][128] k-major) -> fp16 [128][128] n-major ----
__global__ void wt_k(const float* __restrict__ W1, const float* __restrict__ W2,
                     __half* __restrict__ Wt1, __half* __restrict__ Wt2) {
    int i = blockIdx.x * 256 + threadIdx.x;   // 32768 threads
    const float* W = (i < 16384) ? W1 : W2;
    __half* Wt = (i < 16384) ? Wt1 : Wt2;
    int j = i & 16383;
    int k = j >> 7, n = j & 127;
    Wt[n * 128 + k] = __float2half(W[j]);
}

// ---- MFMA GEMM [nrows,128]@[128,128] -> fp16, fused attention logits ----
__global__ __launch_bounds__(256)
void gemm_mfma_k(const float* __restrict__ Xf, const __half* __restrict__ Xh,
                 const __half* __restrict__ Wt, __half* __restrict__ Yh, int nrows,
                 const float* __restrict__ att_s, const float* __restrict__ att_d,
                 float* __restrict__ asb, float* __restrict__ adb) {
    __shared__ __align__(16) __half cst[4][16 * 128];   // 16 KB
    int lane = threadIdx.x & 63;
    int wid  = threadIdx.x >> 6;
    int n = lane & 15, quad = lane >> 4;
    int row0 = (blockIdx.x * 4 + wid) * 16;

    float atts_r[8], attd_r[8];
#pragma unroll
    for (int t = 0; t < 8; ++t) {
        atts_r[t] = att_s[t * 16 + n];
        attd_r[t] = att_d[t * 16 + n];
    }

    float4_t acc[8];
#pragma unroll
    for (int t = 0; t < 8; ++t) acc[t] = (float4_t){0.f, 0.f, 0.f, 0.f};
    int rA = row0 + n; if (rA >= nrows) rA = nrows - 1;
#pragma unroll
    for (int ch = 0; ch < 4; ++ch) {
        half8_t a;
        if (Xh) {
            a = __builtin_nontemporal_load(
                    (const half8_t*)(Xh + (size_t)rA * 128 + ch * 32 + quad * 8));
        } else {
            const float4_t* xp = (const float4_t*)(Xf + (size_t)rA * 128 + ch * 32 + quad * 8);
            float4_t f0 = __builtin_nontemporal_load(xp);
            float4_t f1 = __builtin_nontemporal_load(xp + 1);
            a = (half8_t){(_Float16)f0.x, (_Float16)f0.y, (_Float16)f0.z, (_Float16)f0.w,
                          (_Float16)f1.x, (_Float16)f1.y, (_Float16)f1.z, (_Float16)f1.w};
        }
#pragma unroll
        for (int t = 0; t < 8; ++t) {
            half8_t b = *(const half8_t*)(Wt + (t * 16 + n) * 128 + ch * 32 + quad * 8);
            acc[t] = __builtin_amdgcn_mfma_f32_16x16x32_f16(a, b, acc[t], 0, 0, 0);
        }
    }

    // fused alpha: reduce acc * att over the 16 col-lanes of each quad
#pragma unroll
    for (int rg = 0; rg < 4; ++rg) {
        float ps[4], pd[4];
#pragma unroll
        for (int h = 0; h < 4; ++h) {
            ps[h] = acc[2*h][rg] * atts_r[2*h] + acc[2*h+1][rg] * atts_r[2*h+1];
            pd[h] = acc[2*h][rg] * attd_r[2*h] + acc[2*h+1][rg] * attd_r[2*h+1];
#pragma unroll
            for (int mask = 1; mask < 16; mask <<= 1) {
                ps[h] += __shfl_xor(ps[h], mask, 64);
                pd[h] += __shfl_xor(pd[h], mask, 64);
            }
        }
        int row = row0 + quad * 4 + rg;
        if (n == 0 && row < nrows) {
#pragma unroll
            for (int h = 0; h < 4; ++h) {
                asb[row * 4 + h] = ps[h];
                adb[row * 4 + h] = pd[h];
            }
        }
    }

    // C store: stage fp16 tile in LDS, then coalesced row writes
#pragma unroll
    for (int rg = 0; rg < 4; ++rg)
#pragma unroll
        for (int t = 0; t < 8; ++t)
            cst[wid][(quad * 4 + rg) * 128 + t * 16 + n] = __float2half(acc[t][rg]);
    __syncthreads();
    {
        int chunk = lane & 15;
        int rsub  = lane >> 4;
#pragma unroll
        for (int it = 0; it < 4; ++it) {
            int row = it * 4 + rsub;
            int grow = row0 + row;
            if (grow < nrows) {
                half8_t v = *(const half8_t*)(&cst[wid][row * 128 + chunk * 8]);
                *(half8_t*)(Yh + (size_t)grow * 128 + chunk * 8) = v;
            }
        }
    }
}

// ---- fused softmax + aggregation + bias + ELU (+ optional layer-3 projection) ----
// half-wave (32 lanes) per node, 4 channels per lane, 8 edges in flight
// (straight depth-8 loop: manual prefetch/deeper MLP both measured slower)
__global__ __launch_bounds__(256)
void agg_k(const __half* __restrict__ Hh, const float* __restrict__ asb,
           const float* __restrict__ adb, const int* __restrict__ rp,
           const int* __restrict__ csr, const float* __restrict__ bias,
           __half* __restrict__ Y,
           const float* __restrict__ W3, const float* __restrict__ s3w,
           const float* __restrict__ d3w, float* __restrict__ h3,
           float* __restrict__ as3, float* __restrict__ ad3) {
    int lane = threadIdx.x & 63;
    int hw = lane >> 5;
    int l  = lane & 31;                   // owns channels l*4 .. l*4+3
    int n = blockIdx.x * 8 + (threadIdx.x >> 6) * 2 + hw;
    if (n >= NN) return;
    int hd = l >> 3;
    float ad = adb[n * 4 + hd];
    float acc0 = 0.f, acc1 = 0.f, acc2 = 0.f, acc3 = 0.f, den = 0.f;
    int e = rp[n], end = rp[n + 1], last = end - 1;
    for (int base = e; base < end; base += 8) {
        int s[8]; float a[8]; float2 hraw[8];
#pragma unroll
        for (int j = 0; j < 8; ++j) {
            int i = base + j;
            s[j] = csr[i <= last ? i : last];
        }
#pragma unroll
        for (int j = 0; j < 8; ++j) a[j] = asb[s[j] * 4 + hd] + ad;
#pragma unroll
        for (int j = 0; j < 8; ++j)
            hraw[j] = ((const float2*)(Hh + (size_t)s[j] * 128))[l];
#pragma unroll
        for (int j = 0; j < 8; ++j) {
            float w = __expf(leaky(a[j]));
            w = (base + j <= last) ? w : 0.f;   // mask duplicated tail edges
            den += w;
            const __half2* hp = (const __half2*)&hraw[j];
            float2 f01 = __half22float2(hp[0]);
            float2 f23 = __half22float2(hp[1]);
            acc0 += w * f01.x; acc1 += w * f01.y;
            acc2 += w * f23.x; acc3 += w * f23.y;
        }
    }
    float4 bv = ((const float4*)bias)[l];
    float inv = 1.f / den;
    float o0 = elu_f(acc0 * inv + bv.x);
    float o1 = elu_f(acc1 * inv + bv.y);
    float o2 = elu_f(acc2 * inv + bv.z);
    float o3 = elu_f(acc3 * inv + bv.w);
    if (!W3) {
        half4 hv;
        hv.a = __floats2half2_rn(o0, o1);
        hv.b = __floats2half2_rn(o2, o3);
        ((half4*)(Y + (size_t)n * 128))[l] = hv;
    } else {
        float4 wa = ((const float4*)W3)[l * 2];
        float4 wb = ((const float4*)W3)[l * 2 + 1];
        float p0 = o0 * wa.x + o1 * wa.z + o2 * wb.x + o3 * wb.z;
        float p1 = o0 * wa.y + o1 * wa.w + o2 * wb.y + o3 * wb.w;
        for (int off = 16; off > 0; off >>= 1) {
            p0 += __shfl_down(p0, off, 32);
            p1 += __shfl_down(p1, off, 32);
        }
        if (l == 0) {
            h3[n * 2 + 0] = p0;
            h3[n * 2 + 1] = p1;
            as3[n] = p0 * s3w[0] + p1 * s3w[1];
            ad3[n] = p0 * d3w[0] + p1 * d3w[1];
        }
    }
}

// ---- layer-3 aggregation + log_softmax ----
__global__ void l3agg_k(const float* __restrict__ h3, const float* __restrict__ as3,
                        const float* __restrict__ ad3, const int* __restrict__ rp,
                        const int* __restrict__ csr, const float* __restrict__ b3,
                        float* __restrict__ out) {
    int n = blockIdx.x * blockDim.x + threadIdx.x;
    if (n >= NN) return;
    const float2* h2 = (const float2*)h3;
    float adn = ad3[n];
    float den = 0.f, a0 = 0.f, a1 = 0.f;
    int e = rp[n], end = rp[n + 1], last = end - 1;
    for (int base = e; base < end; base += 4) {
        int s[4]; float al[4]; float2 g[4];
#pragma unroll
        for (int j = 0; j < 4; ++j) {
            int i = base + j;
            s[j] = csr[i <= last ? i : last];
        }
#pragma unroll
        for (int j = 0; j < 4; ++j) al[j] = as3[s[j]] + adn;
#pragma unroll
        for (int j = 0; j < 4; ++j) g[j] = h2[s[j]];
#pragma unroll
        for (int j = 0; j < 4; ++j) {
            float w = __expf(leaky(al[j]));
            w = (base + j <= last) ? w : 0.f;
            den += w;
            a0 += w * g[j].x;
            a1 += w * g[j].y;
        }
    }
    float o0 = a0 / den + b3[0];
    float o1 = a1 / den + b3[1];
    float m = fmaxf(o0, o1);
    float lse = m + logf(__expf(o0 - m) + __expf(o1 - m));
    out[n * 2 + 0] = o0 - lse;
    out[n * 2 + 1] = o1 - lse;
}

extern "C" void kernel_launch(void* const* d_in, const int* in_sizes, int n_in,
                              void* d_out, int out_size, void* d_ws, size_t ws_size,
                              hipStream_t stream) {
    const float* x   = (const float*)d_in[0];
    const int*   ei  = (const int*)d_in[1];
    const float* W1  = (const float*)d_in[2];
    const float* as1 = (const float*)d_in[3];
    const float* ad1 = (const float*)d_in[4];
    const float* b1  = (const float*)d_in[5];
    const float* W2  = (const float*)d_in[6];
    const float* as2 = (const float*)d_in[7];
    const float* ad2 = (const float*)d_in[8];
    const float* b2  = (const float*)d_in[9];
    const float* W3  = (const float*)d_in[10];
    const float* s3w = (const float*)d_in[11];
    const float* d3w = (const float*)d_in[12];
    const float* b3  = (const float*)d_in[13];
    float* out = (float*)d_out;

    char* ws = (char*)d_ws;
    size_t off = 0;
    auto alloc = [&](size_t bytes) -> char* {
        char* p = ws + off;
        off = (off + bytes + 255) & ~(size_t)255;
        return p;
    };
    __half* hA    = (__half*)alloc((size_t)NN * 128 * 2);   // fp16 gather table
    __half* hBh   = (__half*)alloc((size_t)NN * 128 * 2);   // agg1 out (gemm2 in, fp16)
    float* asb    = (float*)alloc((size_t)NN * 4 * 4);
    float* adb    = (float*)alloc((size_t)NN * 4 * 4);
    int*   rp     = (int*)alloc((size_t)(NN + 1) * 4);
    int*   counts = (int*)alloc((size_t)NN * 4);
    int*   csr    = (int*)alloc((size_t)ET * 4);
    int*   rank   = (int*)alloc((size_t)ET * 4);
    int*   bsums  = (int*)alloc((size_t)NBLK * 4);
    __half* Wt1   = (__half*)alloc(128 * 128 * 2);
    __half* Wt2   = (__half*)alloc(128 * 128 * 2);
    float* h3     = (float*)alloc((size_t)NN * 2 * 4);
    float* s3     = (float*)alloc((size_t)NN * 4);
    float* d3     = (float*)alloc((size_t)NN * 4);

    // weight transposes (fp16), independent of everything else
    wt_k<<<128, 256, 0, stream>>>(W1, W2, Wt1, Wt2);

    // CSR by destination (shared by all 3 layers)
    (void)hipMemsetAsync(counts, 0, (size_t)NN * 4, stream);
    hist_k<<<(ET + 255) / 256, 256, 0, stream>>>(ei, counts, rank);
    scan1_k<<<NBLK, 256, 0, stream>>>(counts, rp, bsums);
    scan2_k<<<1, 64, 0, stream>>>(bsums, rp);
    scan3_k<<<NBLK, 256, 0, stream>>>(rp, bsums);
    scatter_k<<<(ET + 255) / 256, 256, 0, stream>>>(ei, rp, rank, csr);

    // Layer 1 (alpha fused into gemm epilogue)
    gemm_mfma_k<<<(NN + 63) / 64, 256, 0, stream>>>(x, nullptr, Wt1, hA, NN,
                                                    as1, ad1, asb, adb);
    agg_k<<<(NN + 7) / 8, 256, 0, stream>>>(hA, asb, adb, rp, csr, b1, hBh,
                                            nullptr, nullptr, nullptr,
                                            nullptr, nullptr, nullptr);

    // Layer 2 (+ fused layer-3 projection/logits in agg epilogue)
    gemm_mfma_k<<<(NN + 63) / 64, 256, 0, stream>>>(nullptr, hBh, Wt2, hA, NN,
                                                    as2, ad2, asb, adb);
    agg_k<<<(NN + 7) / 8, 256, 0, stream>>>(hA, asb, adb, rp, csr, b2, nullptr,
                                            W3, s3w, d3w, h3, s3, d3);

    // Layer 3 aggregation + log_softmax
    l3agg_k<<<(NN + 255) / 256, 256, 0, stream>>>(h3, s3, d3, rp, csr, b3, out);
}